// Round 11
// baseline (304.212 us; speedup 1.0000x reference)
//
#include <hip/hip_runtime.h>
#include <hip/hip_bf16.h>

#define BB 8
#define SS 4096
#define HH 2048
#define EE 32
#define FF 128

constexpr size_t DELTA_N = (size_t)BB * SS * HH;  // 67108864
constexpr size_t WELEM = (size_t)EE * FF * HH;    // 8388608 elems per weight tensor
constexpr size_t WBYTES = WELEM * 2;              // 16 MB packed bf16
constexpr size_t HB16_BYTES = (size_t)BB * SS * HH * 2;  // 128 MB

typedef short bf16x8 __attribute__((ext_vector_type(8)));
typedef float f32x4 __attribute__((ext_vector_type(4)));
typedef unsigned short u16;
typedef __attribute__((address_space(3))) unsigned char as3u8;
typedef __attribute__((address_space(1))) const unsigned char as1u8;

#define WAITV(N)                                             \
  do {                                                       \
    asm volatile("s_waitcnt vmcnt(" #N ")" ::: "memory");    \
    __builtin_amdgcn_sched_barrier(0);                       \
  } while (0)
#define BARRIER()                                            \
  do {                                                       \
    __builtin_amdgcn_s_barrier();                            \
    __builtin_amdgcn_sched_barrier(0);                       \
  } while (0)

__device__ __forceinline__ u16 f2bfu(float x) {
  unsigned int u = __float_as_uint(x);
  u = (u + 0x7FFFu + ((u >> 16) & 1u)) >> 16;  // RNE
  return (u16)u;
}

__device__ __forceinline__ unsigned int pk2(float a, float b) {
  union { __hip_bfloat162 h; unsigned int u; } c;
  c.h = __float22bfloat162_rn(make_float2(a, b));
  return c.u;
}

__device__ __forceinline__ bf16x8 pack8(float4 a, float4 b) {
  union { bf16x8 v; unsigned int u[4]; } r;
  r.u[0] = pk2(a.x, a.y);
  r.u[1] = pk2(a.z, a.w);
  r.u[2] = pk2(b.x, b.y);
  r.u[3] = pk2(b.z, b.w);
  return r.v;
}

__device__ __forceinline__ void glds16(const void* g, void* l) {
  __builtin_amdgcn_global_load_lds((as1u8*)g, (as3u8*)l, 16, 0, 0);
}

// ---------------- k_zero ----------------
__global__ void k_zero(float* __restrict__ ws, int n) {
  int i = blockIdx.x * 256 + threadIdx.x;
  if (i < n) ws[i] = 0.0f;
}

// ---------------- k_pack: weights -> bf16 LDS-image order (proven r8/r10) --------
__global__ void k_pack(const float* __restrict__ w1, const float* __restrict__ w2,
                       u16* __restrict__ w1p, u16* __restrict__ w2p) {
  unsigned c = blockIdx.x * 256 + threadIdx.x;
  const float* src;
  u16* dst;
  if (c < 1048576u) {
    unsigned e = c >> 15, ci = c & 32767u;
    unsigned it = ci >> 10;
    unsigned cb = (ci & 1023u) * 16u;
    unsigned col = cb >> 7;
    unsigned kb = (cb & 127u) ^ ((col & 7u) << 4);
    unsigned k = it * 64u + (kb >> 1);
    src = w1 + ((size_t)(e * 128u + col) * HH + k);
    dst = w1p + (size_t)c * 8;
  } else {
    unsigned c2 = c - 1048576u;
    unsigned e = c2 >> 15, ci = c2 & 32767u;
    unsigned h = ci >> 4;
    unsigned cb = (ci & 15u) * 16u;
    unsigned kb = cb ^ ((h & 7u) << 4);
    unsigned f = kb >> 1;
    src = w2 + ((size_t)(e * 2048u + h) * FF + f);
    dst = w2p + (size_t)c2 * 8;
  }
  float4 a = *(const float4*)src;
  float4 b = *(const float4*)(src + 4);
  *(bf16x8*)dst = pack8(a, b);
}

// ---------------- k_pooltile (proven) ----------------
__global__ __launch_bounds__(512) void k_pooltile(const float* __restrict__ hidden,
                                                  u16* __restrict__ hb16,
                                                  float* __restrict__ psum) {
  const int b  = blockIdx.x >> 6;
  const int st = blockIdx.x & 63;
  const int t  = threadIdx.x;

  const float* src = hidden + ((size_t)b * SS + st * 64) * HH + t * 4;
  char* dbase = (char*)hb16 + (size_t)(b * 64 + st) * 262144 + (size_t)(t >> 4) * 8192;
  const int kq = (t & 15) * 8;

  float4 s = make_float4(0.f, 0.f, 0.f, 0.f);
  for (int r = 0; r < 64; ++r) {
    float4 v = *(const float4*)(src + (size_t)r * HH);
    s.x += v.x; s.y += v.y; s.z += v.z; s.w += v.w;
    *(uint2*)(dbase + r * 128 + (kq ^ ((r & 7) << 4))) =
        make_uint2(pk2(v.x, v.y), pk2(v.z, v.w));
  }
  float* pp = psum + (size_t)b * HH + t * 4;
  atomicAdd(pp + 0, s.x);
  atomicAdd(pp + 1, s.y);
  atomicAdd(pp + 2, s.z);
  atomicAdd(pp + 3, s.w);
}

// ---------------- k_logits (proven) ----------------
__global__ void k_logits(const float* __restrict__ psum, const float* __restrict__ rw,
                         float* __restrict__ logits) {
  int b = blockIdx.x >> 5;
  int e = blockIdx.x & 31;
  int tid = threadIdx.x;
  float acc = 0.0f;
  const float* ps = psum + (size_t)b * HH;
  const float* wr = rw + (size_t)e * HH;
  for (int h = tid; h < HH; h += 256) acc = fmaf(ps[h], wr[h], acc);
  __shared__ float red[256];
  red[tid] = acc;
  __syncthreads();
  for (int w = 128; w > 0; w >>= 1) {
    if (tid < w) red[tid] += red[tid + w];
    __syncthreads();
  }
  if (tid == 0) logits[blockIdx.x] = red[0] * (1.0f / (float)SS);
}

// ---------------- k_topk (proven) ----------------
__global__ void k_topk(const float* __restrict__ logits, const float* __restrict__ rb,
                       const float* __restrict__ counts, const float* __restrict__ drift,
                       int* __restrict__ sel, float* __restrict__ pscale,
                       float* __restrict__ out) {
  int t = threadIdx.x;
  int b = t >> 5, e = t & 31;
  float total = 0.0f, cmax = 0.0f, dmax = 0.0f;
  for (int i = 0; i < EE; ++i) {
    float c = counts[i]; total += c; cmax = fmaxf(cmax, c);
    float d = drift[i];  dmax = fmaxf(dmax, d);
  }
  float cnt = counts[e], dr = drift[e];
  float usage = cnt / fmaxf(total, 1e-8f);
  float bonus = (total > 0.0f) ? 0.1f * (1.0f - usage) : 0.0f;
  float un = cnt / fmaxf(cmax, 1e-8f);
  float dn = dr / fmaxf(dmax, 1e-8f);
  float l = logits[t] + rb[e] + bonus - 0.05f * (un + dn);

  float m = l;
  for (int w = 16; w; w >>= 1) m = fmaxf(m, __shfl_xor(m, w, 32));
  float p = expf(l - m);
  float ssum = p;
  for (int w = 16; w; w >>= 1) ssum += __shfl_xor(ssum, w, 32);
  float prob = p / ssum;
  out[DELTA_N + 32 + t] = prob;

  float v1 = prob; int i1 = e;
  for (int w = 16; w; w >>= 1) {
    float ov = __shfl_xor(v1, w, 32); int oi = __shfl_xor(i1, w, 32);
    if (ov > v1 || (ov == v1 && oi < i1)) { v1 = ov; i1 = oi; }
  }
  float v2 = (e == i1) ? -1.0f : prob; int i2 = e;
  for (int w = 16; w; w >>= 1) {
    float ov = __shfl_xor(v2, w, 32); int oi = __shfl_xor(i2, w, 32);
    if (ov > v2 || (ov == v2 && oi < i2)) { v2 = ov; i2 = oi; }
  }
  if (e == 0) {
    float denom = fmaxf(v1 + v2, 1e-8f);
    float tp0 = v1 / denom, tp1 = v2 / denom;
    sel[b * 2 + 0] = i1;
    sel[b * 2 + 1] = i2;
    pscale[b * 2 + 0] = tp0;
    pscale[b * 2 + 1] = tp1;
    out[DELTA_N + 0 + b * 2 + 0] = (float)i1;
    out[DELTA_N + 0 + b * 2 + 1] = (float)i2;
    out[DELTA_N + 16 + b * 2 + 0] = tp0;
    out[DELTA_N + 16 + b * 2 + 1] = tp1;
  }
}

// ---------------- k_ffn4: M=128, 1 blk/CU, low LDS-bytes/MFMA ----------------
// grid 256: b = bid&7 (XCD), st = bid>>3 (0..31), rows [st*128, +128). 512 thr = 8 waves.
// GEMM1: M=128 N=256 K=2048 BK=64; waves 2x4 (64x64/wave); A dbuf [0,32K), B dbuf [32K,96K).
// GEMM2: M=128 N=2048 K=256; waves 2(row)x4(col); 64-col chunks (32 iters);
//        A-frags pa[4][8] in regs; B dbuf [64K,96K)+[96K,128K); sG [0,64K).
// Bias double-buffered in regs (no per-iter vmcnt drain).
__global__ __launch_bounds__(512, 2) void k_ffn4(
    const u16* __restrict__ hb16, const float* __restrict__ bs1,
    const float* __restrict__ bs2, const u16* __restrict__ w1p,
    const u16* __restrict__ w2p, const int* __restrict__ sel,
    const float* __restrict__ pscale, float* __restrict__ out) {
  __shared__ __align__(16) char smem[131072];

  const int t    = threadIdx.x;
  const int lane = t & 63;
  const int wv   = t >> 6;
  const int l15  = lane & 15;
  const int lk   = lane >> 4;

  const int bid = blockIdx.x;
  const int b   = bid & 7;
  const int st  = bid >> 3;

  const int e0 = sel[2 * b], e1 = sel[2 * b + 1];
  const float p0 = pscale[2 * b], p1 = pscale[2 * b + 1];

  // ---------------- GEMM1 ----------------
  const int wr = wv >> 2, wc = wv & 3;
  const int RB = wr * 64, CB = wc * 64;

  const char* hsrcA = (const char*)hb16 + (size_t)(b * 64 + st * 2) * 262144;
  const size_t eB1 = (size_t)((wv < 4) ? e0 : e1) * 524288;
  const char* bsrc = (const char*)w1p + eB1 + (size_t)(wv & 3) * 4096 + (size_t)lane * 16;

  f32x4 zero = {0.f, 0.f, 0.f, 0.f};
  f32x4 acc1[4][4];
#pragma unroll
  for (int i = 0; i < 4; ++i)
#pragma unroll
    for (int j = 0; j < 4; ++j) acc1[i][j] = zero;

  // stage tile j into buffer bb: 2 A glds + 4 B glds = 6 vmcnt items / thread
  auto STAGE1 = [&](int bb, int j) {
    glds16(hsrcA + (size_t)j * 8192 + (size_t)t * 16,
           &smem[bb * 16384 + (size_t)t * 16]);
    glds16(hsrcA + 262144 + (size_t)j * 8192 + (size_t)t * 16,
           &smem[bb * 16384 + 8192 + (size_t)t * 16]);
    const char* s = bsrc + (size_t)j * 16384;
    char* d = &smem[32768 + bb * 32768 + wv * 4096 + lane * 16];
#pragma unroll
    for (int r = 0; r < 4; ++r) glds16(s + r * 1024, d + r * 1024);
  };

  STAGE1(0, 0);
  STAGE1(1, 1);

#pragma unroll 1
  for (int j = 0; j < 32; ++j) {
    if (j < 31) { WAITV(6); } else { WAITV(0); }
    BARRIER();
    const int cb = j & 1;
    const char* sa = &smem[cb * 16384];
    const char* sb = &smem[32768 + cb * 32768];
#pragma unroll
    for (int kk = 0; kk < 2; ++kk) {
      bf16x8 af[4], bv[4];
#pragma unroll
      for (int rt = 0; rt < 4; ++rt) {
        int row = RB + rt * 16 + l15;
        int sub = row >> 6, r64 = row & 63;
        af[rt] = *(const bf16x8*)(sa + sub * 8192 + r64 * 128 +
                                  ((kk * 64 + lk * 16) ^ ((r64 & 7) << 4)));
      }
#pragma unroll
      for (int ct = 0; ct < 4; ++ct) {
        int col = CB + ct * 16 + l15;
        bv[ct] = *(const bf16x8*)(sb + col * 128 +
                                  ((kk * 64 + lk * 16) ^ ((col & 7) << 4)));
      }
#pragma unroll
      for (int rt = 0; rt < 4; ++rt)
#pragma unroll
        for (int ct = 0; ct < 4; ++ct)
          acc1[rt][ct] = __builtin_amdgcn_mfma_f32_16x16x32_bf16(af[rt], bv[ct], acc1[rt][ct], 0, 0, 0);
    }
    BARRIER();
    if (j < 30) STAGE1(j & 1, j + 2);
  }

  // ---------------- epilogue 1: gelu -> sG [0,64K) ----------------
#pragma unroll
  for (int ct = 0; ct < 4; ++ct) {
    int c = CB + ct * 16 + l15;
    int ec = (c < 128) ? e0 : e1;
    float pc = (c < 128) ? p0 : p1;
    float bias = bs1[ec * FF + (c & 127)];
#pragma unroll
    for (int rt = 0; rt < 4; ++rt)
#pragma unroll
      for (int r = 0; r < 4; ++r) {
        int row = RB + rt * 16 + lk * 4 + r;
        float x = acc1[rt][ct][r] + bias;
        float g = 0.5f * x * (1.0f + erff(x * 0.70710678118654752f));
        *(u16*)&smem[row * 512 + ((c * 2) ^ ((row & 7) << 4))] = f2bfu(pc * g);
      }
  }

  // ---------------- GEMM2 staging prologue ----------------
  // chunk n: cols [n*64, n*64+64). dest: hh*512 + ex*256 + inner. wave stages hh [wv*8,+8).
  const char* w2c0 = (const char*)w2p + (size_t)e0 * 524288;
  const char* w2c1 = (const char*)w2p + (size_t)e1 * 524288;
  const char* wsel = (lane & 16) ? w2c1 : w2c0;
  const int hh_l = wv * 8 + (lane >> 5);   // + i*2 per glds
  const int inb  = (lane & 15) * 16;
  auto STAGE2 = [&](int bb, int n) {
    char* d = &smem[65536 + bb * 32768 + wv * 4096 + lane * 16];
#pragma unroll
    for (int i = 0; i < 4; ++i)
      glds16(wsel + (size_t)(n * 64 + hh_l + i * 2) * 256 + inb, d + i * 1024);
  };
  STAGE2(0, 0);
  STAGE2(1, 1);

  // bias prologue (reg double-buffer)
  const int wr2 = wv & 1, wc2 = wv >> 1;
  const int colf = wc2 * 16 + l15;
  float cb0 = bs2[(size_t)e0 * HH + colf];
  float cb1 = bs2[(size_t)e1 * HH + colf];

  __syncthreads();  // sG ready for all waves

  // preload A-frags: pa[4][8] (128 VGPR)
  bf16x8 pa[4][8];
#pragma unroll
  for (int rt = 0; rt < 4; ++rt) {
    int row = wr2 * 64 + rt * 16 + l15;
    unsigned sw = (row & 7) << 4;
#pragma unroll
    for (int ks = 0; ks < 8; ++ks)
      pa[rt][ks] = *(const bf16x8*)&smem[row * 512 + ((ks * 64 + lk * 16) ^ sw)];
  }

  float* obase = out + ((size_t)b * SS + st * 128) * HH;

  // ---------------- GEMM2: 32 iters x 64 cols ----------------
#pragma unroll 1
  for (int n0 = 0; n0 < 32; ++n0) {
    WAITV(4);
    BARRIER();
    float nb0 = 0.f, nb1 = 0.f;
    if (n0 < 31) {
      nb0 = bs2[(size_t)e0 * HH + (n0 + 1) * 64 + colf];
      nb1 = bs2[(size_t)e1 * HH + (n0 + 1) * 64 + colf];
    }
    const int cb2 = n0 & 1;
    const char* tb = &smem[65536 + cb2 * 32768];
    f32x4 acc2[4];
#pragma unroll
    for (int i = 0; i < 4; ++i) acc2[i] = zero;
#pragma unroll
    for (int ks = 0; ks < 8; ++ks) {
      bf16x8 bv = *(const bf16x8*)(tb + colf * 512 + (ks >> 2) * 256 +
                                   (((ks & 3) * 64 + lk * 16) ^ ((colf & 7) << 4)));
#pragma unroll
      for (int rt = 0; rt < 4; ++rt)
        acc2[rt] = __builtin_amdgcn_mfma_f32_16x16x32_bf16(pa[rt][ks], bv, acc2[rt], 0, 0, 0);
    }
    BARRIER();
    float bias = p0 * cb0 + p1 * cb1;
    const int col = n0 * 64 + colf;
#pragma unroll
    for (int rt = 0; rt < 4; ++rt)
#pragma unroll
      for (int r = 0; r < 4; ++r) {
        int row = wr2 * 64 + rt * 16 + lk * 4 + r;
        obase[(size_t)row * HH + col] = acc2[rt][r] + bias;
      }
    cb0 = nb0;
    cb1 = nb1;
    if (n0 < 30) STAGE2(n0 & 1, n0 + 2);
  }
}

// ================= fallback (round-5 proven, needs no packed ws) =================
__global__ void k_pool_logits(const float* __restrict__ hidden,
                              const float* __restrict__ rw,
                              float* __restrict__ logits) {
  const int b  = blockIdx.x >> 6;
  const int hc = (blockIdx.x >> 3) & 7;
  const int sq = blockIdx.x & 7;
  const int t  = threadIdx.x;
  const int tx = t & 63;
  const int qq = t >> 6;
  const int h0 = hc * 256;

  const float* p = hidden + ((size_t)b * SS + sq * 512 + qq * 128) * HH + h0 + tx * 4;
  float4 s = make_float4(0.f, 0.f, 0.f, 0.f);
  for (int i = 0; i < 128; ++i) {
    float4 v = *(const float4*)(p + (size_t)i * HH);
    s.x += v.x; s.y += v.y; s.z += v.z; s.w += v.w;
  }
  __shared__ float ps[4][256];
  __shared__ float pl[256];
  *(float4*)&ps[qq][tx * 4] = s;
  __syncthreads();
  pl[t] = ps[0][t] + ps[1][t] + ps[2][t] + ps[3][t];
  __syncthreads();

  const int e = t >> 3, part = t & 7;
  const float* wrp = rw + (size_t)e * HH + h0 + part * 32;
  float v = 0.f;
#pragma unroll
  for (int m = 0; m < 32; ++m) v += pl[part * 32 + m] * wrp[m];
  v += __shfl_xor(v, 1, 8);
  v += __shfl_xor(v, 2, 8);
  v += __shfl_xor(v, 4, 8);
  if (part == 0) atomicAdd(&logits[b * EE + e], v * (1.0f / (float)SS));
}

__global__ __launch_bounds__(512, 2) void k_ffn_fb(
    const float* __restrict__ hidden, const float* __restrict__ w1,
    const float* __restrict__ b1, const float* __restrict__ w2,
    const float* __restrict__ b2, const int* __restrict__ sel,
    const float* __restrict__ pscale, float* __restrict__ out) {
  __shared__ unsigned char sA[2][64 * 128];
  __shared__ unsigned char sG[64 * 512];

  const int t    = threadIdx.x;
  const int lane = t & 63;
  const int wv   = t >> 6;
  const int wr   = wv >> 2;
  const int wc   = wv & 3;
  const int l15  = lane & 15;
  const int lk   = lane >> 4;

  const int bid = blockIdx.x;
  const int b   = bid & 7;
  const int s0  = (bid >> 3) * 64;

  const int e0 = sel[2 * b], e1 = sel[2 * b + 1];
  const float p0 = pscale[2 * b], p1 = pscale[2 * b + 1];

  const float* hbase = hidden + ((size_t)b * SS + s0) * HH;
  const int srow = t >> 4;
  const int skq  = t & 15;

  float4 R[2];
  const float* wp[4];
#pragma unroll
  for (int ct = 0; ct < 4; ++ct) {
    int cbase = wc * 64 + ct * 16;
    int ec = (cbase < 128) ? e0 : e1;
    int f  = (cbase & 127) + l15;
    wp[ct] = w1 + ((size_t)ec * FF + f) * HH + lk * 8;
  }

  f32x4 zero = {0.f, 0.f, 0.f, 0.f};
  f32x4 acc1[2][4];
#pragma unroll
  for (int i = 0; i < 2; ++i)
#pragma unroll
    for (int j = 0; j < 4; ++j) acc1[i][j] = zero;

#pragma unroll
  for (int p = 0; p < 2; ++p)
    R[p] = *(const float4*)(hbase + (size_t)(srow + 32 * p) * HH + skq * 4);
#pragma unroll
  for (int p = 0; p < 2; ++p) {
    int row = srow + 32 * p;
    int addr = row * 128 + ((skq * 8) ^ ((row & 7) << 4));
    *(uint2*)(&sA[0][addr]) = make_uint2(pk2(R[p].x, R[p].y), pk2(R[p].z, R[p].w));
  }
  __syncthreads();

  for (int it = 0; it < 32; ++it) {
    const int buf = it & 1;
    if (it < 31) {
      const int k0 = (it + 1) * 64;
#pragma unroll
      for (int p = 0; p < 2; ++p)
        R[p] = *(const float4*)(hbase + (size_t)(srow + 32 * p) * HH + k0 + skq * 4);
    }
#pragma unroll
    for (int kk = 0; kk < 2; ++kk) {
      bf16x8 a[2];
#pragma unroll
      for (int rt = 0; rt < 2; ++rt) {
        int row = wr * 32 + rt * 16 + l15;
        a[rt] = *(const bf16x8*)(&sA[buf][row * 128 + ((kk * 64 + lk * 16) ^ ((row & 7) << 4))]);
      }
#pragma unroll
      for (int ct = 0; ct < 4; ++ct) {
        const float* q = wp[ct] + it * 64 + kk * 32;
        bf16x8 bfr = pack8(*(const float4*)q, *(const float4*)(q + 4));
#pragma unroll
        for (int rt = 0; rt < 2; ++rt)
          acc1[rt][ct] = __builtin_amdgcn_mfma_f32_16x16x32_bf16(a[rt], bfr, acc1[rt][ct], 0, 0, 0);
      }
    }
    if (it < 31) {
#pragma unroll
      for (int p = 0; p < 2; ++p) {
        int row = srow + 32 * p;
        int addr = row * 128 + ((skq * 8) ^ ((row & 7) << 4));
        *(uint2*)(&sA[buf ^ 1][addr]) = make_uint2(pk2(R[p].x, R[p].y), pk2(R[p].z, R[p].w));
      }
    }
    __syncthreads();
  }

#pragma unroll
  for (int ct = 0; ct < 4; ++ct) {
    int c = wc * 64 + ct * 16 + l15;
    int ec = (c < 128) ? e0 : e1;
    float pc = (c < 128) ? p0 : p1;
    float bias = b1[ec * FF + (c & 127)];
#pragma unroll
    for (int rt = 0; rt < 2; ++rt)
#pragma unroll
      for (int r = 0; r < 4; ++r) {
        int row = wr * 32 + rt * 16 + lk * 4 + r;
        float x = acc1[rt][ct][r] + bias;
        float g = 0.5f * x * (1.0f + erff(x * 0.70710678118654752f));
        int addr = row * 512 + ((c * 2) ^ ((row & 7) << 4));
        *(u16*)(&sG[addr]) = f2bfu(pc * g);
      }
  }
  __syncthreads();

  bf16x8 pa[2][8];
#pragma unroll
  for (int rt = 0; rt < 2; ++rt) {
    int row = wr * 32 + rt * 16 + l15;
#pragma unroll
    for (int ks = 0; ks < 8; ++ks)
      pa[rt][ks] = *(const bf16x8*)(&sG[row * 512 + ((ks * 64 + lk * 16) ^ ((row & 7) << 4))]);
  }

  float* obase = out + ((size_t)b * SS + s0) * HH;
  for (int ct = 0; ct < 32; ++ct) {
    const int h = wc * 512 + ct * 16 + l15;
    f32x4 acc[2];
    acc[0] = zero; acc[1] = zero;
    const float* q0 = w2 + ((size_t)e0 * HH + h) * FF + lk * 8;
    const float* q1 = w2 + ((size_t)e1 * HH + h) * FF + lk * 8;
#pragma unroll
    for (int ks = 0; ks < 8; ++ks) {
      const float* q = (ks < 4 ? q0 : q1) + (ks & 3) * 32;
      bf16x8 bfr = pack8(*(const float4*)q, *(const float4*)(q + 4));
#pragma unroll
      for (int rt = 0; rt < 2; ++rt)
        acc[rt] = __builtin_amdgcn_mfma_f32_16x16x32_bf16(pa[rt][ks], bfr, acc[rt], 0, 0, 0);
    }
    float bias = p0 * b2[(size_t)e0 * HH + h] + p1 * b2[(size_t)e1 * HH + h];
#pragma unroll
    for (int rt = 0; rt < 2; ++rt)
#pragma unroll
      for (int r = 0; r < 4; ++r) {
        int row = wr * 32 + rt * 16 + lk * 4 + r;
        obase[(size_t)row * HH + h] = acc[rt][r] + bias;
      }
  }
}

extern "C" void kernel_launch(void* const* d_in, const int* in_sizes, int n_in,
                              void* d_out, int out_size, void* d_ws, size_t ws_size,
                              hipStream_t stream) {
  const float* hidden   = (const float*)d_in[0];
  const float* router_w = (const float*)d_in[1];
  const float* router_b = (const float*)d_in[2];
  const float* w1       = (const float*)d_in[3];
  const float* b1       = (const float*)d_in[4];
  const float* w2       = (const float*)d_in[5];
  const float* b2       = (const float*)d_in[6];
  const float* counts   = (const float*)d_in[7];
  const float* drift    = (const float*)d_in[8];
  float* out            = (float*)d_out;

  float* logits = (float*)d_ws;                     // 256 f @ 0
  int*   sel    = (int*)((char*)d_ws + 1024);       // 16 int
  float* pscale = (float*)((char*)d_ws + 1088);     // 16 f
  float* psum   = (float*)((char*)d_ws + 4096);     // BB*HH f (64KB)

  const size_t need_big = 131072 + 2 * WBYTES + HB16_BYTES;

  if (ws_size >= need_big) {
    u16* w1p  = (u16*)((char*)d_ws + 131072);
    u16* w2p  = (u16*)((char*)d_ws + 131072 + WBYTES);
    u16* hb16 = (u16*)((char*)d_ws + 131072 + 2 * WBYTES);
    k_zero<<<68, 256, 0, stream>>>(logits, 17408);
    k_pack<<<8192, 256, 0, stream>>>(w1, w2, w1p, w2p);
    k_pooltile<<<512, 512, 0, stream>>>(hidden, hb16, psum);
    k_logits<<<256, 256, 0, stream>>>(psum, router_w, logits);
    k_topk<<<1, 256, 0, stream>>>(logits, router_b, counts, drift, sel, pscale, out);
    k_ffn4<<<256, 512, 0, stream>>>(hb16, b1, b2, w1p, w2p, sel, pscale, out);
  } else {
    k_zero<<<2, 256, 0, stream>>>(logits, 288);
    k_pool_logits<<<512, 256, 0, stream>>>(hidden, router_w, logits);
    k_topk<<<1, 256, 0, stream>>>(logits, router_b, counts, drift, sel, pscale, out);
    k_ffn_fb<<<512, 512, 0, stream>>>(hidden, w1, b1, w2, b2, sel, pscale, out);
  }
}

// Round 12
// 260.779 us; speedup vs baseline: 1.1666x; 1.1666x over previous
//
#include <hip/hip_runtime.h>
#include <hip/hip_bf16.h>

#define BB 8
#define SS 4096
#define HH 2048
#define EE 32
#define FF 128

constexpr size_t DELTA_N = (size_t)BB * SS * HH;  // 67108864
constexpr size_t WELEM = (size_t)EE * FF * HH;    // 8388608 elems per weight tensor
constexpr size_t WBYTES = WELEM * 2;              // 16 MB packed bf16
constexpr size_t HB16_BYTES = (size_t)BB * SS * HH * 2;  // 128 MB

typedef short bf16x8 __attribute__((ext_vector_type(8)));
typedef float f32x4 __attribute__((ext_vector_type(4)));
typedef unsigned short u16;
typedef __attribute__((address_space(3))) unsigned char as3u8;
typedef __attribute__((address_space(1))) const unsigned char as1u8;

#define WAITV(N)                                             \
  do {                                                       \
    asm volatile("s_waitcnt vmcnt(" #N ")" ::: "memory");    \
    __builtin_amdgcn_sched_barrier(0);                       \
  } while (0)
#define BARRIER()                                            \
  do {                                                       \
    __builtin_amdgcn_s_barrier();                            \
    __builtin_amdgcn_sched_barrier(0);                       \
  } while (0)

__device__ __forceinline__ u16 f2bfu(float x) {
  unsigned int u = __float_as_uint(x);
  u = (u + 0x7FFFu + ((u >> 16) & 1u)) >> 16;  // RNE
  return (u16)u;
}

__device__ __forceinline__ unsigned int pk2(float a, float b) {
  union { __hip_bfloat162 h; unsigned int u; } c;
  c.h = __float22bfloat162_rn(make_float2(a, b));
  return c.u;
}

__device__ __forceinline__ bf16x8 pack8(float4 a, float4 b) {
  union { bf16x8 v; unsigned int u[4]; } r;
  r.u[0] = pk2(a.x, a.y);
  r.u[1] = pk2(a.z, a.w);
  r.u[2] = pk2(b.x, b.y);
  r.u[3] = pk2(b.z, b.w);
  return r.v;
}

__device__ __forceinline__ void glds16(const void* g, void* l) {
  __builtin_amdgcn_global_load_lds((as1u8*)g, (as3u8*)l, 16, 0, 0);
}

// ---------------- k_zero ----------------
__global__ void k_zero(float* __restrict__ ws, int n) {
  int i = blockIdx.x * 256 + threadIdx.x;
  if (i < n) ws[i] = 0.0f;
}

// ---------------- k_poolpack: merged pooltile (bid<512) + weight pack (bid>=512) --
// pooltile: psum column sums + bf16 swizzled hidden image (proven body).
// pack: weights -> bf16 LDS-image order (proven math, c = (bid-512)*4096 + i*512 + t).
__global__ __launch_bounds__(512) void k_poolpack(
    const float* __restrict__ hidden, const float* __restrict__ w1,
    const float* __restrict__ w2, u16* __restrict__ hb16,
    float* __restrict__ psum, u16* __restrict__ w1p, u16* __restrict__ w2p) {
  const int bid = blockIdx.x;
  const int t = threadIdx.x;
  if (bid < 512) {
    const int b  = bid >> 6;
    const int st = bid & 63;
    const float* src = hidden + ((size_t)b * SS + st * 64) * HH + t * 4;
    char* dbase = (char*)hb16 + (size_t)(b * 64 + st) * 262144 + (size_t)(t >> 4) * 8192;
    const int kq = (t & 15) * 8;
    float4 s = make_float4(0.f, 0.f, 0.f, 0.f);
    for (int r = 0; r < 64; ++r) {
      float4 v = *(const float4*)(src + (size_t)r * HH);
      s.x += v.x; s.y += v.y; s.z += v.z; s.w += v.w;
      *(uint2*)(dbase + r * 128 + (kq ^ ((r & 7) << 4))) =
          make_uint2(pk2(v.x, v.y), pk2(v.z, v.w));
    }
    float* pp = psum + (size_t)b * HH + t * 4;
    atomicAdd(pp + 0, s.x);
    atomicAdd(pp + 1, s.y);
    atomicAdd(pp + 2, s.z);
    atomicAdd(pp + 3, s.w);
  } else {
    const int pb = bid - 512;
#pragma unroll 1
    for (int i = 0; i < 8; ++i) {
      unsigned c = (unsigned)pb * 4096u + (unsigned)i * 512u + (unsigned)t;
      const float* src;
      u16* dst;
      if (c < 1048576u) {
        unsigned e = c >> 15, ci = c & 32767u;
        unsigned it = ci >> 10;
        unsigned cb = (ci & 1023u) * 16u;
        unsigned col = cb >> 7;
        unsigned kb = (cb & 127u) ^ ((col & 7u) << 4);
        unsigned k = it * 64u + (kb >> 1);
        src = w1 + ((size_t)(e * 128u + col) * HH + k);
        dst = w1p + (size_t)c * 8;
      } else {
        unsigned c2 = c - 1048576u;
        unsigned e = c2 >> 15, ci = c2 & 32767u;
        unsigned h = ci >> 4;
        unsigned cb = (ci & 15u) * 16u;
        unsigned kb = cb ^ ((h & 7u) << 4);
        unsigned f = kb >> 1;
        src = w2 + ((size_t)(e * 2048u + h) * FF + f);
        dst = w2p + (size_t)c2 * 8;
      }
      float4 a = *(const float4*)src;
      float4 b2v = *(const float4*)(src + 4);
      *(bf16x8*)dst = pack8(a, b2v);
    }
  }
}

// ---------------- k_logits (proven) ----------------
__global__ void k_logits(const float* __restrict__ psum, const float* __restrict__ rw,
                         float* __restrict__ logits) {
  int b = blockIdx.x >> 5;
  int e = blockIdx.x & 31;
  int tid = threadIdx.x;
  float acc = 0.0f;
  const float* ps = psum + (size_t)b * HH;
  const float* wr = rw + (size_t)e * HH;
  for (int h = tid; h < HH; h += 256) acc = fmaf(ps[h], wr[h], acc);
  __shared__ float red[256];
  red[tid] = acc;
  __syncthreads();
  for (int w = 128; w > 0; w >>= 1) {
    if (tid < w) red[tid] += red[tid + w];
    __syncthreads();
  }
  if (tid == 0) logits[blockIdx.x] = red[0] * (1.0f / (float)SS);
}

// ---------------- k_topk (proven) ----------------
__global__ void k_topk(const float* __restrict__ logits, const float* __restrict__ rb,
                       const float* __restrict__ counts, const float* __restrict__ drift,
                       int* __restrict__ sel, float* __restrict__ pscale,
                       float* __restrict__ out) {
  int t = threadIdx.x;
  int b = t >> 5, e = t & 31;
  float total = 0.0f, cmax = 0.0f, dmax = 0.0f;
  for (int i = 0; i < EE; ++i) {
    float c = counts[i]; total += c; cmax = fmaxf(cmax, c);
    float d = drift[i];  dmax = fmaxf(dmax, d);
  }
  float cnt = counts[e], dr = drift[e];
  float usage = cnt / fmaxf(total, 1e-8f);
  float bonus = (total > 0.0f) ? 0.1f * (1.0f - usage) : 0.0f;
  float un = cnt / fmaxf(cmax, 1e-8f);
  float dn = dr / fmaxf(dmax, 1e-8f);
  float l = logits[t] + rb[e] + bonus - 0.05f * (un + dn);

  float m = l;
  for (int w = 16; w; w >>= 1) m = fmaxf(m, __shfl_xor(m, w, 32));
  float p = expf(l - m);
  float ssum = p;
  for (int w = 16; w; w >>= 1) ssum += __shfl_xor(ssum, w, 32);
  float prob = p / ssum;
  out[DELTA_N + 32 + t] = prob;

  float v1 = prob; int i1 = e;
  for (int w = 16; w; w >>= 1) {
    float ov = __shfl_xor(v1, w, 32); int oi = __shfl_xor(i1, w, 32);
    if (ov > v1 || (ov == v1 && oi < i1)) { v1 = ov; i1 = oi; }
  }
  float v2 = (e == i1) ? -1.0f : prob; int i2 = e;
  for (int w = 16; w; w >>= 1) {
    float ov = __shfl_xor(v2, w, 32); int oi = __shfl_xor(i2, w, 32);
    if (ov > v2 || (ov == v2 && oi < i2)) { v2 = ov; i2 = oi; }
  }
  if (e == 0) {
    float denom = fmaxf(v1 + v2, 1e-8f);
    float tp0 = v1 / denom, tp1 = v2 / denom;
    sel[b * 2 + 0] = i1;
    sel[b * 2 + 1] = i2;
    pscale[b * 2 + 0] = tp0;
    pscale[b * 2 + 1] = tp1;
    out[DELTA_N + 0 + b * 2 + 0] = (float)i1;
    out[DELTA_N + 0 + b * 2 + 1] = (float)i2;
    out[DELTA_N + 16 + b * 2 + 0] = tp0;
    out[DELTA_N + 16 + b * 2 + 1] = tp1;
  }
}

// ---------------- k_ffn5: r10 GEMM1 + GEMM2 dup2 / LDS-bias / counted vmcnt ------
// grid 512: b = bid&7 (XCD), st = bid>>3. 512 thr = 8 waves. LDS 80KB, 2 blk/CU.
// GEMM1 (waves 2x4): M=64 N=256 K=2048 BK=64. B dbuf [0,64K), A dbuf [64K,80K).
// Epilogue: sG [0,32K) (over dead B-buf0), combined bias [64K,72K) (over dead A).
// GEMM2 (waves 2r x 4c): 32 iters x 64 cols; pa[2][8] regs; tiles 32K dbuf [0,64K).
__global__ __launch_bounds__(512, 4) void k_ffn5(
    const u16* __restrict__ hb16, const float* __restrict__ bs1,
    const float* __restrict__ bs2, const u16* __restrict__ w1p,
    const u16* __restrict__ w2p, const int* __restrict__ sel,
    const float* __restrict__ pscale, float* __restrict__ out) {
  __shared__ __align__(16) char smem[81920];

  const int t    = threadIdx.x;
  const int lane = t & 63;
  const int wv   = t >> 6;
  const int l15  = lane & 15;
  const int lk   = lane >> 4;

  const int bid = blockIdx.x;
  const int b   = bid & 7;
  const int st  = bid >> 3;

  const int e0 = sel[2 * b], e1 = sel[2 * b + 1];
  const float p0 = pscale[2 * b], p1 = pscale[2 * b + 1];

  const int wr = wv >> 2, wc = wv & 3;
  const int RB = wr * 32, CB = wc * 64;

  const char* hsrc = (const char*)hb16 + (size_t)(b * 64 + st) * 262144 + (size_t)t * 16;
  const size_t eB1 = (size_t)((wv < 4) ? e0 : e1) * 524288;
  const char* bsrc = (const char*)w1p + eB1 + (size_t)(wv & 3) * 4096 + (size_t)lane * 16;

  f32x4 zero = {0.f, 0.f, 0.f, 0.f};
  f32x4 acc1[2][4];
#pragma unroll
  for (int i = 0; i < 2; ++i)
#pragma unroll
    for (int j = 0; j < 4; ++j) acc1[i][j] = zero;

  // GEMM1 stage: 1 A glds + 4 B glds = 5 vmcnt items/thread
  auto STAGE1 = [&](int bb, int j) {
    glds16(hsrc + (size_t)j * 8192, &smem[65536 + bb * 8192 + (size_t)t * 16]);
    const char* s = bsrc + (size_t)j * 16384;
    char* d = &smem[bb * 32768 + wv * 4096 + lane * 16];
#pragma unroll
    for (int r = 0; r < 4; ++r) glds16(s + r * 1024, d + r * 1024);
  };

  STAGE1(0, 0);
  STAGE1(1, 1);

#pragma unroll 1
  for (int j = 0; j < 32; ++j) {
    if (j < 31) { WAITV(5); } else { WAITV(0); }
    BARRIER();
    const int cb = j & 1;
    const char* sa = &smem[65536 + cb * 8192];
    const char* sb = &smem[cb * 32768];
#pragma unroll
    for (int kk = 0; kk < 2; ++kk) {
      bf16x8 af[2], bv[4];
#pragma unroll
      for (int rt = 0; rt < 2; ++rt) {
        int row = RB + rt * 16 + l15;
        af[rt] = *(const bf16x8*)(sa + row * 128 + ((kk * 64 + lk * 16) ^ ((row & 7) << 4)));
      }
#pragma unroll
      for (int ct = 0; ct < 4; ++ct) {
        int col = CB + ct * 16 + l15;
        bv[ct] = *(const bf16x8*)(sb + col * 128 + ((kk * 64 + lk * 16) ^ ((col & 7) << 4)));
      }
#pragma unroll
      for (int rt = 0; rt < 2; ++rt)
#pragma unroll
        for (int ct = 0; ct < 4; ++ct)
          acc1[rt][ct] = __builtin_amdgcn_mfma_f32_16x16x32_bf16(af[rt], bv[ct], acc1[rt][ct], 0, 0, 0);
    }
    BARRIER();
    if (j < 30) STAGE1(j & 1, j + 2);
  }

  // ---- epilogue 1: gelu -> sG [0,32K); combined bias -> [64K,72K)
#pragma unroll
  for (int ct = 0; ct < 4; ++ct) {
    int c = CB + ct * 16 + l15;
    int ec = (c < 128) ? e0 : e1;
    float pc = (c < 128) ? p0 : p1;
    float bias = bs1[ec * FF + (c & 127)];
#pragma unroll
    for (int rt = 0; rt < 2; ++rt)
#pragma unroll
      for (int r = 0; r < 4; ++r) {
        int row = RB + rt * 16 + lk * 4 + r;
        float x = acc1[rt][ct][r] + bias;
        float g = 0.5f * x * (1.0f + erff(x * 0.70710678118654752f));
        *(u16*)&smem[row * 512 + ((c * 2) ^ ((row & 7) << 4))] = f2bfu(pc * g);
      }
  }
  {
    float4 q0 = *(const float4*)(bs2 + (size_t)e0 * HH + t * 4);
    float4 q1 = *(const float4*)(bs2 + (size_t)e1 * HH + t * 4);
    float4 bb;
    bb.x = p0 * q0.x + p1 * q1.x;
    bb.y = p0 * q0.y + p1 * q1.y;
    bb.z = p0 * q0.z + p1 * q1.z;
    bb.w = p0 * q0.w + p1 * q1.w;
    *(float4*)&smem[65536 + t * 16] = bb;
  }
  __syncthreads();

  // ---- pa preload from sG: wave (wr2 rows, wc2 cols); pa[2][8] = 64 VGPR
  const int wr2 = wv >> 2, wc2 = wv & 3;
  bf16x8 pa[2][8];
#pragma unroll
  for (int rt = 0; rt < 2; ++rt) {
    int row = wr2 * 32 + rt * 16 + l15;
    unsigned sw = (row & 7) << 4;
#pragma unroll
    for (int ks = 0; ks < 8; ++ks)
      pa[rt][ks] = *(const bf16x8*)&smem[row * 512 + ((ks * 64 + lk * 16) ^ sw)];
  }
  BARRIER();  // all preloads done before tiles overwrite sG region

  // ---- GEMM2 staging: chunk n = cols [n*64,+64), tile 32KB = [ex][h64][256B]
  const char* wse = (const char*)w2p + (size_t)((wv < 4) ? e0 : e1) * 524288;
  auto STAGE2 = [&](int bb, int n) {
    const char* s = wse + (size_t)(n * 64 + (wv & 3) * 16) * 256 + (size_t)lane * 16;
    char* d = &smem[bb * 32768 + (wv >> 2) * 16384 + (wv & 3) * 4096 + lane * 16];
#pragma unroll
    for (int i = 0; i < 4; ++i) glds16(s + i * 1024, d + i * 1024);
  };
  STAGE2(0, 0);
  STAGE2(1, 1);

  float* obase = out + ((size_t)b * SS + st * 64) * HH;
  const int h64 = wc2 * 16 + l15;

  // ---- GEMM2: 32 iters; 2 barriers/iter; waits derived: 8 stores + 4 glds = 12
#pragma unroll 1
  for (int n0 = 0; n0 < 32; ++n0) {
    if (n0 == 0) { WAITV(4); }
    else if (n0 == 31) { WAITV(8); }
    else { WAITV(12); }
    BARRIER();
    const char* tb = &smem[(n0 & 1) * 32768];
    float bias = *(const float*)&smem[65536 + (n0 * 64 + h64) * 4];
    f32x4 acc2[2];
    acc2[0] = zero; acc2[1] = zero;
#pragma unroll
    for (int ks = 0; ks < 8; ++ks) {
      bf16x8 bv = *(const bf16x8*)(tb + (ks >> 2) * 16384 + h64 * 256 +
                                   (((ks & 3) * 64 + lk * 16) ^ ((h64 & 7) << 4)));
#pragma unroll
      for (int rt = 0; rt < 2; ++rt)
        acc2[rt] = __builtin_amdgcn_mfma_f32_16x16x32_bf16(pa[rt][ks], bv, acc2[rt], 0, 0, 0);
    }
    BARRIER();
    const int col = n0 * 64 + h64;
#pragma unroll
    for (int rt = 0; rt < 2; ++rt)
#pragma unroll
      for (int r = 0; r < 4; ++r) {
        int row = wr2 * 32 + rt * 16 + lk * 4 + r;
        obase[(size_t)row * HH + col] = acc2[rt][r] + bias;
      }
    if (n0 < 30) STAGE2(n0 & 1, n0 + 2);
  }
}

// ================= fallback (round-5 proven, needs no packed ws) =================
__global__ void k_pool_logits(const float* __restrict__ hidden,
                              const float* __restrict__ rw,
                              float* __restrict__ logits) {
  const int b  = blockIdx.x >> 6;
  const int hc = (blockIdx.x >> 3) & 7;
  const int sq = blockIdx.x & 7;
  const int t  = threadIdx.x;
  const int tx = t & 63;
  const int qq = t >> 6;
  const int h0 = hc * 256;

  const float* p = hidden + ((size_t)b * SS + sq * 512 + qq * 128) * HH + h0 + tx * 4;
  float4 s = make_float4(0.f, 0.f, 0.f, 0.f);
  for (int i = 0; i < 128; ++i) {
    float4 v = *(const float4*)(p + (size_t)i * HH);
    s.x += v.x; s.y += v.y; s.z += v.z; s.w += v.w;
  }
  __shared__ float ps[4][256];
  __shared__ float pl[256];
  *(float4*)&ps[qq][tx * 4] = s;
  __syncthreads();
  pl[t] = ps[0][t] + ps[1][t] + ps[2][t] + ps[3][t];
  __syncthreads();

  const int e = t >> 3, part = t & 7;
  const float* wrp = rw + (size_t)e * HH + h0 + part * 32;
  float v = 0.f;
#pragma unroll
  for (int m = 0; m < 32; ++m) v += pl[part * 32 + m] * wrp[m];
  v += __shfl_xor(v, 1, 8);
  v += __shfl_xor(v, 2, 8);
  v += __shfl_xor(v, 4, 8);
  if (part == 0) atomicAdd(&logits[b * EE + e], v * (1.0f / (float)SS));
}

__global__ __launch_bounds__(512, 2) void k_ffn_fb(
    const float* __restrict__ hidden, const float* __restrict__ w1,
    const float* __restrict__ b1, const float* __restrict__ w2,
    const float* __restrict__ b2, const int* __restrict__ sel,
    const float* __restrict__ pscale, float* __restrict__ out) {
  __shared__ unsigned char sA[2][64 * 128];
  __shared__ unsigned char sG[64 * 512];

  const int t    = threadIdx.x;
  const int lane = t & 63;
  const int wv   = t >> 6;
  const int wr   = wv >> 2;
  const int wc   = wv & 3;
  const int l15  = lane & 15;
  const int lk   = lane >> 4;

  const int bid = blockIdx.x;
  const int b   = bid & 7;
  const int s0  = (bid >> 3) * 64;

  const int e0 = sel[2 * b], e1 = sel[2 * b + 1];
  const float p0 = pscale[2 * b], p1 = pscale[2 * b + 1];

  const float* hbase = hidden + ((size_t)b * SS + s0) * HH;
  const int srow = t >> 4;
  const int skq  = t & 15;

  float4 R[2];
  const float* wp[4];
#pragma unroll
  for (int ct = 0; ct < 4; ++ct) {
    int cbase = wc * 64 + ct * 16;
    int ec = (cbase < 128) ? e0 : e1;
    int f  = (cbase & 127) + l15;
    wp[ct] = w1 + ((size_t)ec * FF + f) * HH + lk * 8;
  }

  f32x4 zero = {0.f, 0.f, 0.f, 0.f};
  f32x4 acc1[2][4];
#pragma unroll
  for (int i = 0; i < 2; ++i)
#pragma unroll
    for (int j = 0; j < 4; ++j) acc1[i][j] = zero;

#pragma unroll
  for (int p = 0; p < 2; ++p)
    R[p] = *(const float4*)(hbase + (size_t)(srow + 32 * p) * HH + skq * 4);
#pragma unroll
  for (int p = 0; p < 2; ++p) {
    int row = srow + 32 * p;
    int addr = row * 128 + ((skq * 8) ^ ((row & 7) << 4));
    *(uint2*)(&sA[0][addr]) = make_uint2(pk2(R[p].x, R[p].y), pk2(R[p].z, R[p].w));
  }
  __syncthreads();

  for (int it = 0; it < 32; ++it) {
    const int buf = it & 1;
    if (it < 31) {
      const int k0 = (it + 1) * 64;
#pragma unroll
      for (int p = 0; p < 2; ++p)
        R[p] = *(const float4*)(hbase + (size_t)(srow + 32 * p) * HH + k0 + skq * 4);
    }
#pragma unroll
    for (int kk = 0; kk < 2; ++kk) {
      bf16x8 a[2];
#pragma unroll
      for (int rt = 0; rt < 2; ++rt) {
        int row = wr * 32 + rt * 16 + l15;
        a[rt] = *(const bf16x8*)(&sA[buf][row * 128 + ((kk * 64 + lk * 16) ^ ((row & 7) << 4))]);
      }
#pragma unroll
      for (int ct = 0; ct < 4; ++ct) {
        const float* q = wp[ct] + it * 64 + kk * 32;
        bf16x8 bfr = pack8(*(const float4*)q, *(const float4*)(q + 4));
#pragma unroll
        for (int rt = 0; rt < 2; ++rt)
          acc1[rt][ct] = __builtin_amdgcn_mfma_f32_16x16x32_bf16(a[rt], bfr, acc1[rt][ct], 0, 0, 0);
      }
    }
    if (it < 31) {
#pragma unroll
      for (int p = 0; p < 2; ++p) {
        int row = srow + 32 * p;
        int addr = row * 128 + ((skq * 8) ^ ((row & 7) << 4));
        *(uint2*)(&sA[buf ^ 1][addr]) = make_uint2(pk2(R[p].x, R[p].y), pk2(R[p].z, R[p].w));
      }
    }
    __syncthreads();
  }

#pragma unroll
  for (int ct = 0; ct < 4; ++ct) {
    int c = wc * 64 + ct * 16 + l15;
    int ec = (c < 128) ? e0 : e1;
    float pc = (c < 128) ? p0 : p1;
    float bias = b1[ec * FF + (c & 127)];
#pragma unroll
    for (int rt = 0; rt < 2; ++rt)
#pragma unroll
      for (int r = 0; r < 4; ++r) {
        int row = wr * 32 + rt * 16 + lk * 4 + r;
        float x = acc1[rt][ct][r] + bias;
        float g = 0.5f * x * (1.0f + erff(x * 0.70710678118654752f));
        int addr = row * 512 + ((c * 2) ^ ((row & 7) << 4));
        *(u16*)(&sG[addr]) = f2bfu(pc * g);
      }
  }
  __syncthreads();

  bf16x8 pa[2][8];
#pragma unroll
  for (int rt = 0; rt < 2; ++rt) {
    int row = wr * 32 + rt * 16 + l15;
#pragma unroll
    for (int ks = 0; ks < 8; ++ks)
      pa[rt][ks] = *(const bf16x8*)(&sG[row * 512 + ((ks * 64 + lk * 16) ^ ((row & 7) << 4))]);
  }

  float* obase = out + ((size_t)b * SS + s0) * HH;
  for (int ct = 0; ct < 32; ++ct) {
    const int h = wc * 512 + ct * 16 + l15;
    f32x4 acc[2];
    acc[0] = zero; acc[1] = zero;
    const float* q0 = w2 + ((size_t)e0 * HH + h) * FF + lk * 8;
    const float* q1 = w2 + ((size_t)e1 * HH + h) * FF + lk * 8;
#pragma unroll
    for (int ks = 0; ks < 8; ++ks) {
      const float* q = (ks < 4 ? q0 : q1) + (ks & 3) * 32;
      bf16x8 bfr = pack8(*(const float4*)q, *(const float4*)(q + 4));
#pragma unroll
      for (int rt = 0; rt < 2; ++rt)
        acc[rt] = __builtin_amdgcn_mfma_f32_16x16x32_bf16(pa[rt][ks], bfr, acc[rt], 0, 0, 0);
    }
    float bias = p0 * b2[(size_t)e0 * HH + h] + p1 * b2[(size_t)e1 * HH + h];
#pragma unroll
    for (int rt = 0; rt < 2; ++rt)
#pragma unroll
      for (int r = 0; r < 4; ++r) {
        int row = wr * 32 + rt * 16 + lk * 4 + r;
        obase[(size_t)row * HH + h] = acc[rt][r] + bias;
      }
  }
}

extern "C" void kernel_launch(void* const* d_in, const int* in_sizes, int n_in,
                              void* d_out, int out_size, void* d_ws, size_t ws_size,
                              hipStream_t stream) {
  const float* hidden   = (const float*)d_in[0];
  const float* router_w = (const float*)d_in[1];
  const float* router_b = (const float*)d_in[2];
  const float* w1       = (const float*)d_in[3];
  const float* b1       = (const float*)d_in[4];
  const float* w2       = (const float*)d_in[5];
  const float* b2       = (const float*)d_in[6];
  const float* counts   = (const float*)d_in[7];
  const float* drift    = (const float*)d_in[8];
  float* out            = (float*)d_out;

  float* logits = (float*)d_ws;                     // 256 f @ 0
  int*   sel    = (int*)((char*)d_ws + 1024);       // 16 int
  float* pscale = (float*)((char*)d_ws + 1088);     // 16 f
  float* psum   = (float*)((char*)d_ws + 4096);     // BB*HH f (64KB)

  const size_t need_big = 131072 + 2 * WBYTES + HB16_BYTES;

  if (ws_size >= need_big) {
    u16* w1p  = (u16*)((char*)d_ws + 131072);
    u16* w2p  = (u16*)((char*)d_ws + 131072 + WBYTES);
    u16* hb16 = (u16*)((char*)d_ws + 131072 + 2 * WBYTES);
    k_zero<<<68, 256, 0, stream>>>(logits, 17408);
    k_poolpack<<<1024, 512, 0, stream>>>(hidden, w1, w2, hb16, psum, w1p, w2p);
    k_logits<<<256, 256, 0, stream>>>(psum, router_w, logits);
    k_topk<<<1, 256, 0, stream>>>(logits, router_b, counts, drift, sel, pscale, out);
    k_ffn5<<<512, 512, 0, stream>>>(hb16, b1, b2, w1p, w2p, sel, pscale, out);
  } else {
    k_zero<<<2, 256, 0, stream>>>(logits, 288);
    k_pool_logits<<<512, 256, 0, stream>>>(hidden, router_w, logits);
    k_topk<<<1, 256, 0, stream>>>(logits, router_b, counts, drift, sel, pscale, out);
    k_ffn_fb<<<512, 512, 0, stream>>>(hidden, w1, b1, w2, b2, sel, pscale, out);
  }
}